// Round 2
// baseline (1199.419 us; speedup 1.0000x reference)
//
#include <hip/hip_runtime.h>
#include <hip/hip_bf16.h>

#define D 128
#define LDSPAD 136  // 128 + 8 bf16 pad -> 2-way LDS bank aliasing (free)

typedef short s8v __attribute__((ext_vector_type(8)));  // 8 bf16 = 4 VGPRs
typedef short s4v __attribute__((ext_vector_type(4)));  // 4 bf16
typedef float f4v __attribute__((ext_vector_type(4)));  // 4 f32 accum

__device__ inline short f2bf(float f) {
    __hip_bfloat16 h = __float2bfloat16(f);  // RNE
    return *reinterpret_cast<short*>(&h);
}

// silu with v_rcp_f32 (rel err ~1e-6, far below bf16-MFMA error floor)
__device__ inline float fast_silu(float m) {
    return m * __builtin_amdgcn_rcpf(1.f + __expf(-m));
}

// ---------------- prep: weights f32 -> bf16 (once), zero hist ----------------
// blocks [0,80): convert 5 x 128x128 f32 -> bf16 (one float4/thread)
// blocks [80,..): zero cnt[N]
__global__ __launch_bounds__(256) void k_prep(const float* __restrict__ W0,
                                              const float* __restrict__ W1,
                                              const float* __restrict__ W2,
                                              const float* __restrict__ W3,
                                              const float* __restrict__ W4,
                                              short* __restrict__ Wbf,
                                              int* __restrict__ cnt, int N) {
    const int b = blockIdx.x, tid = threadIdx.x;
    if (b < 80) {
        int g = b * 256 + tid;          // float4 index, 5*4096 = 20480 total
        int m = g >> 12;                // matrix id (uniform per block: 16 blk/matrix)
        const float* W = W0;
        if (m == 1) W = W1; else if (m == 2) W = W2;
        else if (m == 3) W = W3; else if (m == 4) W = W4;
        int w = g & 4095;
        float4 v = reinterpret_cast<const float4*>(W)[w];
        s4v o;
        o[0] = f2bf(v.x); o[1] = f2bf(v.y); o[2] = f2bf(v.z); o[3] = f2bf(v.w);
        *reinterpret_cast<s4v*>(&Wbf[(size_t)m * 16384 + w * 4]) = o;
    } else {
        int i = (b - 80) * 256 + tid;
        if (i < N) cnt[i] = 0;
    }
}

// Copy prestaged bf16 W [128][128] into LDS with padded stride. blockDim=256.
__device__ inline void load_wbf_lds(const short* __restrict__ Wb, short* lds) {
    const int tid = threadIdx.x;
    const int4* src = reinterpret_cast<const int4*>(Wb);
#pragma unroll
    for (int i = 0; i < 8; ++i) {
        int f = tid + 256 * i;          // 2048 16B-chunks
        int4 v = src[f];
        int row = f >> 4, c = f & 15;   // 16 chunks per row
        *reinterpret_cast<int4*>(&lds[row * LDSPAD + c * 8]) = v;
    }
}

// Build A-fragments (16 rows of X, f32->bf16) for one 16-row tile.
__device__ inline void build_a(const float* __restrict__ X, int row0, s8v a[4]) {
    const int lane = threadIdx.x & 63;
    const int l15 = lane & 15, q = lane >> 4;
    const float* xr = X + (size_t)(row0 + l15) * D + q * 8;
#pragma unroll
    for (int c = 0; c < 4; ++c) {
        float4 f0 = *reinterpret_cast<const float4*>(xr + c * 32);
        float4 f1 = *reinterpret_cast<const float4*>(xr + c * 32 + 4);
        s8v t;
        t[0] = f2bf(f0.x); t[1] = f2bf(f0.y); t[2] = f2bf(f0.z); t[3] = f2bf(f0.w);
        t[4] = f2bf(f1.x); t[5] = f2bf(f1.y); t[6] = f2bf(f1.z); t[7] = f2bf(f1.w);
        a[c] = t;
    }
}

// MFMA 16x128 tile; B-fragments from LDS (padded layout).
__device__ inline void mfma_b_lds(const s8v a[4], const short* lds, f4v acc[8]) {
    const int lane = threadIdx.x & 63;
    const int l15 = lane & 15, q = lane >> 4;
#pragma unroll
    for (int t = 0; t < 8; ++t) {
        f4v acc_t = {0.f, 0.f, 0.f, 0.f};
#pragma unroll
        for (int c = 0; c < 4; ++c) {
            const s8v b = *reinterpret_cast<const s8v*>(
                &lds[(t * 16 + l15) * LDSPAD + c * 32 + q * 8]);
            acc_t = __builtin_amdgcn_mfma_f32_16x16x32_bf16(a[c], b, acc_t, 0, 0, 0);
        }
        acc[t] = acc_t;
    }
}

// MFMA 16x128 tile; B-fragments straight from global bf16 W (L1-resident, 32KB).
__device__ inline void mfma_b_g(const s8v a[4], const short* __restrict__ Wb,
                                f4v acc[8]) {
    const int lane = threadIdx.x & 63;
    const int l15 = lane & 15, q = lane >> 4;
#pragma unroll
    for (int t = 0; t < 8; ++t) {
        f4v acc_t = {0.f, 0.f, 0.f, 0.f};
#pragma unroll
        for (int c = 0; c < 4; ++c) {
            const s8v b = *reinterpret_cast<const s8v*>(
                &Wb[(t * 16 + l15) * D + c * 32 + q * 8]);
            acc_t = __builtin_amdgcn_mfma_f32_16x16x32_bf16(a[c], b, acc_t, 0, 0, 0);
        }
        acc[t] = acc_t;
    }
}

// ---------------- CSR build ----------------

__global__ __launch_bounds__(256) void k_hist(const int* __restrict__ tidx,
                                              int* __restrict__ cnt, int E) {
    int i = blockIdx.x * 256 + threadIdx.x;
    if (i < E) atomicAdd(&cnt[tidx[i]], 1);
}

// Exclusive scan of cnt[0..n) -> off[0..n]; also copy to cursor. One block.
__global__ __launch_bounds__(1024) void k_scan(const int* __restrict__ cnt,
                                               int* __restrict__ off,
                                               int* __restrict__ cursor, int n) {
    __shared__ int part[1024];
    const int tid = threadIdx.x;
    const int chunk = (n + 1023) / 1024;
    const int lo = tid * chunk;
    const int hi = min(lo + chunk, n);
    int s = 0;
    for (int i = lo; i < hi; ++i) s += cnt[i];
    part[tid] = s;
    __syncthreads();
    for (int d = 1; d < 1024; d <<= 1) {
        int v = (tid >= d) ? part[tid - d] : 0;
        __syncthreads();
        part[tid] += v;
        __syncthreads();
    }
    int run = part[tid] - s;  // exclusive base for this thread's chunk
    for (int i = lo; i < hi; ++i) {
        off[i] = run;
        cursor[i] = run;
        run += cnt[i];
    }
    if (tid == 0) off[n] = part[1023];
}

__global__ __launch_bounds__(256) void k_scatter(const int* __restrict__ tidx,
                                                 int* __restrict__ cursor,
                                                 int* __restrict__ elist, int E) {
    int i = blockIdx.x * 256 + threadIdx.x;
    if (i < E) {
        int p = atomicAdd(&cursor[tidx[i]], 1);
        elist[p] = i;
    }
}

// ---------------- GEMM kernels (no LDS: W is L1-resident bf16) ----------------

// P = X @ W^T, one 16-row tile per wave
__global__ __launch_bounds__(256, 4) void k_gemm1(const float* __restrict__ X,
                                                  const short* __restrict__ Wb,
                                                  float* __restrict__ P, int ntiles) {
    const int lane = threadIdx.x & 63, wave = threadIdx.x >> 6;
    const int l15 = lane & 15, q = lane >> 4;
    const int tile = blockIdx.x * 4 + wave;
    if (tile >= ntiles) return;
    s8v a[4];
    build_a(X, tile * 16, a);
    f4v acc[8];
    mfma_b_g(a, Wb, acc);
#pragma unroll
    for (int t = 0; t < 8; ++t) {
        int col = t * 16 + l15;
#pragma unroll
        for (int r = 0; r < 4; ++r)
            P[(size_t)(tile * 16 + q * 4 + r) * D + col] = acc[t][r];
    }
}

// P1 = X @ W1^T, P2 = X @ W2^T (shared A-fragments; reads X once)
__global__ __launch_bounds__(256, 4) void k_gemm2(const float* __restrict__ X,
                                                  const short* __restrict__ Wb1,
                                                  const short* __restrict__ Wb2,
                                                  float* __restrict__ P1,
                                                  float* __restrict__ P2, int ntiles) {
    const int lane = threadIdx.x & 63, wave = threadIdx.x >> 6;
    const int l15 = lane & 15, q = lane >> 4;
    const int tile = blockIdx.x * 4 + wave;
    if (tile >= ntiles) return;
    s8v a[4];
    build_a(X, tile * 16, a);
    f4v acc1[8], acc2[8];
    mfma_b_g(a, Wb1, acc1);
    mfma_b_g(a, Wb2, acc2);
#pragma unroll
    for (int t = 0; t < 8; ++t) {
        int col = t * 16 + l15;
#pragma unroll
        for (int r = 0; r < 4; ++r) {
            size_t o = (size_t)(tile * 16 + q * 4 + r) * D + col;
            P1[o] = acc1[t][r];
            P2[o] = acc2[t][r];
        }
    }
}

// Per-edge: msg = edge@We2e^T + Ps[sidx] + Pt[tidx]; e_out = edge + LN(silu(msg)).
// Streaming, no atomics. acc is overwritten with silu(m) in place (saves 32 VGPRs).
__global__ __launch_bounds__(256, 4) void k_edge(const float* __restrict__ edge,
                                                 const int* __restrict__ sidx,
                                                 const int* __restrict__ tidx,
                                                 const short* __restrict__ Wb,
                                                 const float* __restrict__ Ps,
                                                 const float* __restrict__ Pt,
                                                 const float* __restrict__ g1,
                                                 const float* __restrict__ b1,
                                                 float* __restrict__ eout,
                                                 int tile0, int tile1) {
    __shared__ short lds[D * LDSPAD];
    load_wbf_lds(Wb, lds);
    __syncthreads();
    const int lane = threadIdx.x & 63, wave = threadIdx.x >> 6;
    const int l15 = lane & 15, q = lane >> 4;
    for (int tile = tile0 + blockIdx.x * 4 + wave; tile < tile1;
         tile += gridDim.x * 4) {
        const int e0 = tile * 16;
        int si[4], ti[4];
#pragma unroll
        for (int r = 0; r < 4; ++r) {      // issue index loads early
            si[r] = sidx[e0 + q * 4 + r];
            ti[r] = tidx[e0 + q * 4 + r];
        }
        s8v a[4];
        build_a(edge, e0, a);
        f4v acc[8];
        mfma_b_lds(a, lds, acc);
        float s1[4] = {0.f, 0.f, 0.f, 0.f}, s2[4] = {0.f, 0.f, 0.f, 0.f};
#pragma unroll
        for (int t = 0; t < 8; ++t) {
            int col = t * 16 + l15;
#pragma unroll
            for (int r = 0; r < 4; ++r) {
                float m = acc[t][r] + Ps[(size_t)si[r] * D + col]
                                    + Pt[(size_t)ti[r] * D + col];
                float hh = fast_silu(m);
                acc[t][r] = hh;            // overwrite in place
                s1[r] += hh;
                s2[r] += hh * hh;
            }
        }
#pragma unroll
        for (int m = 1; m < 16; m <<= 1) {
#pragma unroll
            for (int r = 0; r < 4; ++r) {
                s1[r] += __shfl_xor(s1[r], m, 64);
                s2[r] += __shfl_xor(s2[r], m, 64);
            }
        }
        float mean[4], rstd[4];
#pragma unroll
        for (int r = 0; r < 4; ++r) {
            float mu = s1[r] * (1.f / 128.f);
            float var = s2[r] * (1.f / 128.f) - mu * mu;
            mean[r] = mu;
            rstd[r] = rsqrtf(var + 1e-5f);
        }
#pragma unroll
        for (int t = 0; t < 8; ++t) {
            int col = t * 16 + l15;
            float gg = g1[col], bb = b1[col];
#pragma unroll
            for (int r = 0; r < 4; ++r) {
                int rowg = e0 + q * 4 + r;
                float v = edge[(size_t)rowg * D + col]
                          + ((acc[t][r] - mean[r]) * rstd[r] * gg + bb);
                eout[(size_t)rowg * D + col] = v;
            }
        }
    }
}

// agg[n] = sum of eout rows for edges targeting n. One wave per node (high TLP).
__global__ __launch_bounds__(256) void k_agg(const float* __restrict__ eout,
                                             const int* __restrict__ off,
                                             const int* __restrict__ elist,
                                             float* __restrict__ agg, int N) {
    const int node = blockIdx.x * 4 + (threadIdx.x >> 6);
    const int lane = threadIdx.x & 63;
    if (node >= N) return;
    const int lo = off[node], hi = off[node + 1];
    float ax = 0.f, ay = 0.f;
    for (int j = lo; j < hi; ++j) {
        int e = elist[j];
        float2 v = *reinterpret_cast<const float2*>(&eout[(size_t)e * D + 2 * lane]);
        ax += v.x; ay += v.y;
    }
    float2 o = {ax, ay};
    *reinterpret_cast<float2*>(&agg[(size_t)node * D + 2 * lane]) = o;
}

// tgt_msg = agg@We2t^T + Ptt; tgt_out = tgt + LN(silu(tgt_msg)).
// out == aggIn (in-place): each wave reads its 16 rows fully before writing.
__global__ __launch_bounds__(256, 4) void k_node_update(const float* __restrict__ aggIn,
                                                        const short* __restrict__ Wb,
                                                        const float* __restrict__ Ptt,
                                                        const float* __restrict__ tgt,
                                                        const float* __restrict__ g2,
                                                        const float* __restrict__ b2,
                                                        float* __restrict__ out, int ntiles) {
    const int lane = threadIdx.x & 63, wave = threadIdx.x >> 6;
    const int l15 = lane & 15, q = lane >> 4;
    const int tile = blockIdx.x * 4 + wave;
    if (tile >= ntiles) return;
    const int n0 = tile * 16;
    s8v a[4];
    build_a(aggIn, n0, a);
    f4v acc[8];
    mfma_b_g(a, Wb, acc);
    float s1[4] = {0.f, 0.f, 0.f, 0.f}, s2[4] = {0.f, 0.f, 0.f, 0.f};
#pragma unroll
    for (int t = 0; t < 8; ++t) {
        int col = t * 16 + l15;
#pragma unroll
        for (int r = 0; r < 4; ++r) {
            int rowg = n0 + q * 4 + r;
            float m = acc[t][r] + Ptt[(size_t)rowg * D + col];
            float hh = fast_silu(m);
            acc[t][r] = hh;
            s1[r] += hh;
            s2[r] += hh * hh;
        }
    }
#pragma unroll
    for (int m = 1; m < 16; m <<= 1) {
#pragma unroll
        for (int r = 0; r < 4; ++r) {
            s1[r] += __shfl_xor(s1[r], m, 64);
            s2[r] += __shfl_xor(s2[r], m, 64);
        }
    }
    float mean[4], rstd[4];
#pragma unroll
    for (int r = 0; r < 4; ++r) {
        float mu = s1[r] * (1.f / 128.f);
        float var = s2[r] * (1.f / 128.f) - mu * mu;
        mean[r] = mu;
        rstd[r] = rsqrtf(var + 1e-5f);
    }
#pragma unroll
    for (int t = 0; t < 8; ++t) {
        int col = t * 16 + l15;
        float gg = g2[col], bb = b2[col];
#pragma unroll
        for (int r = 0; r < 4; ++r) {
            int rowg = n0 + q * 4 + r;
            float v = tgt[(size_t)rowg * D + col]
                      + ((acc[t][r] - mean[r]) * rstd[r] * gg + bb);
            out[(size_t)rowg * D + col] = v;
        }
    }
}

extern "C" void kernel_launch(void* const* d_in, const int* in_sizes, int n_in,
                              void* d_out, int out_size, void* d_ws, size_t ws_size,
                              hipStream_t stream) {
    const float* src   = (const float*)d_in[0];
    const float* tgt   = (const float*)d_in[1];
    const float* edge  = (const float*)d_in[2];
    const int*   sidx  = (const int*)d_in[3];
    const int*   tidx  = (const int*)d_in[4];
    const float* W_s2e = (const float*)d_in[5];
    const float* W_t2e = (const float*)d_in[6];
    const float* W_e2e = (const float*)d_in[7];
    const float* W_e2t = (const float*)d_in[8];
    const float* W_t2t = (const float*)d_in[9];
    const float* g1    = (const float*)d_in[10];
    const float* b1    = (const float*)d_in[11];
    const float* g2    = (const float*)d_in[12];
    const float* b2    = (const float*)d_in[13];

    const int N = in_sizes[0] / D;   // 50000
    const int E = in_sizes[3];       // 500000

    float* eout = (float*)d_out;                    // [E,128]
    float* nout = eout + (size_t)E * D;             // [N,128]: agg, then tgt_out in place

    // workspace layout (Wbf first => 16B alignment for int4 loads)
    short* Wbf = (short*)d_ws;                      // 5 x [128][128] bf16
    float* Ps  = (float*)(Wbf + 5 * 16384);         // [N,128] f32
    float* Pt  = Ps + (size_t)N * D;
    float* Ptt = Pt + (size_t)N * D;
    int*   cnt    = (int*)(Ptt + (size_t)N * D);    // [N]
    int*   off    = cnt + N;                        // [N+1]
    int*   cursor = off + N + 1;                    // [N]
    int*   elist  = cursor + N;                     // [E]

    const short* Wb_s2e = Wbf;
    const short* Wb_t2e = Wbf + 1 * 16384;
    const short* Wb_e2e = Wbf + 2 * 16384;
    const short* Wb_e2t = Wbf + 3 * 16384;
    const short* Wb_t2t = Wbf + 4 * 16384;

    // ---- prep: weight conversion + hist zeroing ----
    const int zeroBlocks = (N + 255) / 256;
    k_prep<<<80 + zeroBlocks, 256, 0, stream>>>(W_s2e, W_t2e, W_e2e, W_e2t, W_t2t,
                                                Wbf, cnt, N);

    // ---- CSR build (int atomics only) ----
    k_hist<<<(E + 255) / 256, 256, 0, stream>>>(tidx, cnt, E);
    k_scan<<<1, 1024, 0, stream>>>(cnt, off, cursor, N);
    k_scatter<<<(E + 255) / 256, 256, 0, stream>>>(tidx, cursor, elist, E);

    // ---- node-side transforms (no LDS, W from L1) ----
    const int ntilesN = N >> 4;
    const int nodeBlocks = (ntilesN + 3) / 4;
    k_gemm1<<<nodeBlocks, 256, 0, stream>>>(src, Wb_s2e, Ps, ntilesN);
    k_gemm2<<<nodeBlocks, 256, 0, stream>>>(tgt, Wb_t2e, Wb_t2t, Pt, Ptt, ntilesN);

    // ---- edge update (streaming), split in two for profiler visibility ----
    const int ntilesE = E >> 4;
    const int halfE = ntilesE >> 1;
    k_edge<<<1024, 256, 0, stream>>>(edge, sidx, tidx, Wb_e2e, Ps, Pt, g1, b1,
                                     eout, 0, halfE);
    k_edge<<<1024, 256, 0, stream>>>(edge, sidx, tidx, Wb_e2e, Ps, Pt, g1, b1,
                                     eout, halfE, ntilesE);

    // ---- deterministic aggregation + node update ----
    k_agg<<<(N + 3) / 4, 256, 0, stream>>>(eout, off, elist, nout, N);
    k_node_update<<<nodeBlocks, 256, 0, stream>>>(nout, Wb_e2t, Ptt, tgt, g2, b2,
                                                  nout, ntilesN);
}

// Round 3
// 884.191 us; speedup vs baseline: 1.3565x; 1.3565x over previous
//
#include <hip/hip_runtime.h>
#include <hip/hip_bf16.h>

#define D 128
#define LDSPAD 136  // 128 + 8 bf16 pad -> 2-way LDS bank aliasing (free)

typedef short s8v __attribute__((ext_vector_type(8)));  // 8 bf16 = 4 VGPRs
typedef short s4v __attribute__((ext_vector_type(4)));  // 4 bf16
typedef float f4v __attribute__((ext_vector_type(4)));  // 4 f32 accum

__device__ inline short f2bf(float f) {
    __hip_bfloat16 h = __float2bfloat16(f);  // RNE
    return *reinterpret_cast<short*>(&h);
}

// silu with v_rcp_f32 (rel err ~1e-6, far below bf16-MFMA error floor)
__device__ inline float fast_silu(float m) {
    return m * __builtin_amdgcn_rcpf(1.f + __expf(-m));
}

// ---------------- prep: weights f32 -> bf16 (once), zero hist ----------------
// blocks [0,80): convert 5 x 128x128 f32 -> bf16 (one float4/thread)
// blocks [80,..): zero cnt[N]
__global__ __launch_bounds__(256) void k_prep(const float* __restrict__ W0,
                                              const float* __restrict__ W1,
                                              const float* __restrict__ W2,
                                              const float* __restrict__ W3,
                                              const float* __restrict__ W4,
                                              short* __restrict__ Wbf,
                                              int* __restrict__ cnt, int N) {
    const int b = blockIdx.x, tid = threadIdx.x;
    if (b < 80) {
        int g = b * 256 + tid;          // float4 index, 5*4096 = 20480 total
        int m = g >> 12;                // matrix id (uniform per block: 16 blk/matrix)
        const float* W = W0;
        if (m == 1) W = W1; else if (m == 2) W = W2;
        else if (m == 3) W = W3; else if (m == 4) W = W4;
        int w = g & 4095;
        float4 v = reinterpret_cast<const float4*>(W)[w];
        s4v o;
        o[0] = f2bf(v.x); o[1] = f2bf(v.y); o[2] = f2bf(v.z); o[3] = f2bf(v.w);
        *reinterpret_cast<s4v*>(&Wbf[(size_t)m * 16384 + w * 4]) = o;
    } else {
        int i = (b - 80) * 256 + tid;
        if (i < N) cnt[i] = 0;
    }
}

// Convert 128x128 f32 W (row-major) into LDS bf16 with padded stride.
// Requires blockDim.x == 256.   (round-0 exact)
__device__ inline void load_w_lds(const float* __restrict__ W, short* lds) {
    const int tid = threadIdx.x;
    const float4* W4 = reinterpret_cast<const float4*>(W);
#pragma unroll
    for (int i = 0; i < 16; ++i) {
        int f = tid + 256 * i;          // 0..4095 float4s
        float4 v = W4[f];
        int row = f >> 5;               // /32 float4s per row
        int c4  = (f & 31) * 4;
        short* p = &lds[row * LDSPAD + c4];
        p[0] = f2bf(v.x); p[1] = f2bf(v.y);
        p[2] = f2bf(v.z); p[3] = f2bf(v.w);
    }
}

// One wave computes a 16x128 tile of X @ W^T via 8 col-tiles x 4 k-chunks
// of v_mfma_f32_16x16x32_bf16. X is f32 [rows][128]; W is bf16 in LDS.
// (round-0 exact)
__device__ inline void mfma_tile(const float* __restrict__ X, int row0,
                                 const short* lds, f4v acc[8]) {
    const int lane = threadIdx.x & 63;
    const int l15 = lane & 15, q = lane >> 4;
    s8v a[4];
    const float* xr = X + (size_t)(row0 + l15) * D + q * 8;
#pragma unroll
    for (int c = 0; c < 4; ++c) {
        float4 f0 = *reinterpret_cast<const float4*>(xr + c * 32);
        float4 f1 = *reinterpret_cast<const float4*>(xr + c * 32 + 4);
        s8v t;
        t[0] = f2bf(f0.x); t[1] = f2bf(f0.y); t[2] = f2bf(f0.z); t[3] = f2bf(f0.w);
        t[4] = f2bf(f1.x); t[5] = f2bf(f1.y); t[6] = f2bf(f1.z); t[7] = f2bf(f1.w);
        a[c] = t;
    }
#pragma unroll
    for (int t = 0; t < 8; ++t) {
        f4v acc_t = {0.f, 0.f, 0.f, 0.f};
#pragma unroll
        for (int c = 0; c < 4; ++c) {
            const s8v b = *reinterpret_cast<const s8v*>(
                &lds[(t * 16 + l15) * LDSPAD + c * 32 + q * 8]);
            acc_t = __builtin_amdgcn_mfma_f32_16x16x32_bf16(a[c], b, acc_t, 0, 0, 0);
        }
        acc[t] = acc_t;
    }
}

// Build A-fragments (16 rows of X, f32->bf16) for one 16-row tile.
__device__ inline void build_a(const float* __restrict__ X, int row0, s8v a[4]) {
    const int lane = threadIdx.x & 63;
    const int l15 = lane & 15, q = lane >> 4;
    const float* xr = X + (size_t)(row0 + l15) * D + q * 8;
#pragma unroll
    for (int c = 0; c < 4; ++c) {
        float4 f0 = *reinterpret_cast<const float4*>(xr + c * 32);
        float4 f1 = *reinterpret_cast<const float4*>(xr + c * 32 + 4);
        s8v t;
        t[0] = f2bf(f0.x); t[1] = f2bf(f0.y); t[2] = f2bf(f0.z); t[3] = f2bf(f0.w);
        t[4] = f2bf(f1.x); t[5] = f2bf(f1.y); t[6] = f2bf(f1.z); t[7] = f2bf(f1.w);
        a[c] = t;
    }
}

// MFMA 16x128 tile; B-fragments straight from global bf16 W (L2-resident, 32KB).
__device__ inline void mfma_b_g(const s8v a[4], const short* __restrict__ Wb,
                                f4v acc[8]) {
    const int lane = threadIdx.x & 63;
    const int l15 = lane & 15, q = lane >> 4;
#pragma unroll
    for (int t = 0; t < 8; ++t) {
        f4v acc_t = {0.f, 0.f, 0.f, 0.f};
#pragma unroll
        for (int c = 0; c < 4; ++c) {
            const s8v b = *reinterpret_cast<const s8v*>(
                &Wb[(t * 16 + l15) * D + c * 32 + q * 8]);
            acc_t = __builtin_amdgcn_mfma_f32_16x16x32_bf16(a[c], b, acc_t, 0, 0, 0);
        }
        acc[t] = acc_t;
    }
}

// ---------------- CSR build ----------------

__global__ __launch_bounds__(256) void k_hist(const int* __restrict__ tidx,
                                              int* __restrict__ cnt, int E) {
    int i = blockIdx.x * 256 + threadIdx.x;
    if (i < E) atomicAdd(&cnt[tidx[i]], 1);
}

// Exclusive scan of cnt[0..n) -> off[0..n]; also copy to cursor. One block.
__global__ __launch_bounds__(1024) void k_scan(const int* __restrict__ cnt,
                                               int* __restrict__ off,
                                               int* __restrict__ cursor, int n) {
    __shared__ int part[1024];
    const int tid = threadIdx.x;
    const int chunk = (n + 1023) / 1024;
    const int lo = tid * chunk;
    const int hi = min(lo + chunk, n);
    int s = 0;
    for (int i = lo; i < hi; ++i) s += cnt[i];
    part[tid] = s;
    __syncthreads();
    for (int d = 1; d < 1024; d <<= 1) {
        int v = (tid >= d) ? part[tid - d] : 0;
        __syncthreads();
        part[tid] += v;
        __syncthreads();
    }
    int run = part[tid] - s;  // exclusive base for this thread's chunk
    for (int i = lo; i < hi; ++i) {
        off[i] = run;
        cursor[i] = run;
        run += cnt[i];
    }
    if (tid == 0) off[n] = part[1023];
}

__global__ __launch_bounds__(256) void k_scatter(const int* __restrict__ tidx,
                                                 int* __restrict__ cursor,
                                                 int* __restrict__ elist, int E) {
    int i = blockIdx.x * 256 + threadIdx.x;
    if (i < E) {
        int p = atomicAdd(&cursor[tidx[i]], 1);
        elist[p] = i;
    }
}

// ---------------- node-side GEMMs, fused into one launch ----------------
// blocks [0,nb):   Ps  = src @ Ws2e^T
// blocks [nb,2nb): Pt  = tgt @ Wt2e^T,  Ptt = tgt @ Wt2t^T  (shared A-frags)
__global__ __launch_bounds__(256) void k_gemms(const float* __restrict__ src,
                                               const float* __restrict__ tgt,
                                               const short* __restrict__ Wb_s2e,
                                               const short* __restrict__ Wb_t2e,
                                               const short* __restrict__ Wb_t2t,
                                               float* __restrict__ Ps,
                                               float* __restrict__ Pt,
                                               float* __restrict__ Ptt,
                                               int ntiles, int nb) {
    const int lane = threadIdx.x & 63, wave = threadIdx.x >> 6;
    const int l15 = lane & 15, q = lane >> 4;
    if ((int)blockIdx.x < nb) {
        const int tile = blockIdx.x * 4 + wave;
        if (tile >= ntiles) return;
        s8v a[4];
        build_a(src, tile * 16, a);
        f4v acc[8];
        mfma_b_g(a, Wb_s2e, acc);
#pragma unroll
        for (int t = 0; t < 8; ++t) {
            int col = t * 16 + l15;
#pragma unroll
            for (int r = 0; r < 4; ++r)
                Ps[(size_t)(tile * 16 + q * 4 + r) * D + col] = acc[t][r];
        }
    } else {
        const int tile = (blockIdx.x - nb) * 4 + wave;
        if (tile >= ntiles) return;
        s8v a[4];
        build_a(tgt, tile * 16, a);
        f4v acc1[8], acc2[8];
        mfma_b_g(a, Wb_t2e, acc1);
        mfma_b_g(a, Wb_t2t, acc2);
#pragma unroll
        for (int t = 0; t < 8; ++t) {
            int col = t * 16 + l15;
#pragma unroll
            for (int r = 0; r < 4; ++r) {
                size_t o = (size_t)(tile * 16 + q * 4 + r) * D + col;
                Pt[o] = acc1[t][r];
                Ptt[o] = acc2[t][r];
            }
        }
    }
}

// Per-edge: msg = edge@We2e^T + Ps[sidx] + Pt[tidx]; e_out = edge + LN(silu(msg)).
// ROUND-0 EXACT BODY (VGPR 144 config) + [tile0,tile1) split for profiler
// visibility. Higher occupancy was measured to cause ~2x fetch/write
// amplification via L2 partial-line eviction — do not cap VGPRs here.
__global__ __launch_bounds__(256) void k_edge(const float* __restrict__ edge,
                                              const int* __restrict__ sidx,
                                              const int* __restrict__ tidx,
                                              const float* __restrict__ W,
                                              const float* __restrict__ Ps,
                                              const float* __restrict__ Pt,
                                              const float* __restrict__ g1,
                                              const float* __restrict__ b1,
                                              float* __restrict__ eout,
                                              int tile0, int tile1) {
    __shared__ short lds[D * LDSPAD];
    load_w_lds(W, lds);
    __syncthreads();
    const int lane = threadIdx.x & 63, wave = threadIdx.x >> 6;
    const int l15 = lane & 15, q = lane >> 4;
    for (int tile = tile0 + blockIdx.x * 4 + wave; tile < tile1;
         tile += gridDim.x * 4) {
        const int e0 = tile * 16;
        f4v acc[8];
        mfma_tile(edge, e0, lds, acc);
        int si[4], ti[4];
#pragma unroll
        for (int r = 0; r < 4; ++r) {
            si[r] = sidx[e0 + q * 4 + r];
            ti[r] = tidx[e0 + q * 4 + r];
        }
        float h[8][4];
        float s1[4] = {0.f, 0.f, 0.f, 0.f}, s2[4] = {0.f, 0.f, 0.f, 0.f};
#pragma unroll
        for (int t = 0; t < 8; ++t) {
            int col = t * 16 + l15;
#pragma unroll
            for (int r = 0; r < 4; ++r) {
                float m = acc[t][r] + Ps[(size_t)si[r] * D + col]
                                    + Pt[(size_t)ti[r] * D + col];
                float hh = m / (1.f + __expf(-m));   // silu
                h[t][r] = hh;
                s1[r] += hh;
                s2[r] += hh * hh;
            }
        }
#pragma unroll
        for (int m = 1; m < 16; m <<= 1) {
#pragma unroll
            for (int r = 0; r < 4; ++r) {
                s1[r] += __shfl_xor(s1[r], m, 64);
                s2[r] += __shfl_xor(s2[r], m, 64);
            }
        }
        float mean[4], rstd[4];
#pragma unroll
        for (int r = 0; r < 4; ++r) {
            float mu = s1[r] * (1.f / 128.f);
            float var = s2[r] * (1.f / 128.f) - mu * mu;
            mean[r] = mu;
            rstd[r] = rsqrtf(var + 1e-5f);
        }
#pragma unroll
        for (int t = 0; t < 8; ++t) {
            int col = t * 16 + l15;
            float gg = g1[col], bb = b1[col];
#pragma unroll
            for (int r = 0; r < 4; ++r) {
                int rowg = e0 + q * 4 + r;
                float v = edge[(size_t)rowg * D + col]
                          + ((h[t][r] - mean[r]) * rstd[r] * gg + bb);
                eout[(size_t)rowg * D + col] = v;
            }
        }
    }
}

// agg[n] = sum of eout rows for edges targeting n. One wave per node.
// Unroll-4: 4 independent 512B row-gathers in flight (eout is LLC-resident).
__global__ __launch_bounds__(256) void k_agg(const float* __restrict__ eout,
                                             const int* __restrict__ off,
                                             const int* __restrict__ elist,
                                             float* __restrict__ agg, int N) {
    const int node = blockIdx.x * 4 + (threadIdx.x >> 6);
    const int lane = threadIdx.x & 63;
    if (node >= N) return;
    const int lo = off[node], hi = off[node + 1];
    float ax = 0.f, ay = 0.f;
    int j = lo;
    for (; j + 4 <= hi; j += 4) {
        int e0 = elist[j], e1 = elist[j + 1], e2 = elist[j + 2], e3 = elist[j + 3];
        float2 v0 = *reinterpret_cast<const float2*>(&eout[(size_t)e0 * D + 2 * lane]);
        float2 v1 = *reinterpret_cast<const float2*>(&eout[(size_t)e1 * D + 2 * lane]);
        float2 v2 = *reinterpret_cast<const float2*>(&eout[(size_t)e2 * D + 2 * lane]);
        float2 v3 = *reinterpret_cast<const float2*>(&eout[(size_t)e3 * D + 2 * lane]);
        ax += v0.x + v1.x + v2.x + v3.x;
        ay += v0.y + v1.y + v2.y + v3.y;
    }
    for (; j < hi; ++j) {
        int e = elist[j];
        float2 v = *reinterpret_cast<const float2*>(&eout[(size_t)e * D + 2 * lane]);
        ax += v.x; ay += v.y;
    }
    float2 o = {ax, ay};
    *reinterpret_cast<float2*>(&agg[(size_t)node * D + 2 * lane]) = o;
}

// tgt_msg = agg@We2t^T + Ptt; tgt_out = tgt + LN(silu(tgt_msg)).
// out == aggIn (in-place): each wave reads its 16 rows fully before writing.
// Streaming kernel: occupancy cap is safe (no gathers).
__global__ __launch_bounds__(256, 4) void k_node_update(const float* __restrict__ aggIn,
                                                        const short* __restrict__ Wb,
                                                        const float* __restrict__ Ptt,
                                                        const float* __restrict__ tgt,
                                                        const float* __restrict__ g2,
                                                        const float* __restrict__ b2,
                                                        float* __restrict__ out, int ntiles) {
    const int lane = threadIdx.x & 63, wave = threadIdx.x >> 6;
    const int l15 = lane & 15, q = lane >> 4;
    const int tile = blockIdx.x * 4 + wave;
    if (tile >= ntiles) return;
    const int n0 = tile * 16;
    s8v a[4];
    build_a(aggIn, n0, a);
    f4v acc[8];
    mfma_b_g(a, Wb, acc);
    float s1[4] = {0.f, 0.f, 0.f, 0.f}, s2[4] = {0.f, 0.f, 0.f, 0.f};
#pragma unroll
    for (int t = 0; t < 8; ++t) {
        int col = t * 16 + l15;
#pragma unroll
        for (int r = 0; r < 4; ++r) {
            int rowg = n0 + q * 4 + r;
            float m = acc[t][r] + Ptt[(size_t)rowg * D + col];
            float hh = fast_silu(m);
            acc[t][r] = hh;
            s1[r] += hh;
            s2[r] += hh * hh;
        }
    }
#pragma unroll
    for (int m = 1; m < 16; m <<= 1) {
#pragma unroll
        for (int r = 0; r < 4; ++r) {
            s1[r] += __shfl_xor(s1[r], m, 64);
            s2[r] += __shfl_xor(s2[r], m, 64);
        }
    }
    float mean[4], rstd[4];
#pragma unroll
    for (int r = 0; r < 4; ++r) {
        float mu = s1[r] * (1.f / 128.f);
        float var = s2[r] * (1.f / 128.f) - mu * mu;
        mean[r] = mu;
        rstd[r] = rsqrtf(var + 1e-5f);
    }
#pragma unroll
    for (int t = 0; t < 8; ++t) {
        int col = t * 16 + l15;
        float gg = g2[col], bb = b2[col];
#pragma unroll
        for (int r = 0; r < 4; ++r) {
            int rowg = n0 + q * 4 + r;
            float v = tgt[(size_t)rowg * D + col]
                      + ((acc[t][r] - mean[r]) * rstd[r] * gg + bb);
            out[(size_t)rowg * D + col] = v;
        }
    }
}

extern "C" void kernel_launch(void* const* d_in, const int* in_sizes, int n_in,
                              void* d_out, int out_size, void* d_ws, size_t ws_size,
                              hipStream_t stream) {
    const float* src   = (const float*)d_in[0];
    const float* tgt   = (const float*)d_in[1];
    const float* edge  = (const float*)d_in[2];
    const int*   sidx  = (const int*)d_in[3];
    const int*   tidx  = (const int*)d_in[4];
    const float* W_s2e = (const float*)d_in[5];
    const float* W_t2e = (const float*)d_in[6];
    const float* W_e2e = (const float*)d_in[7];
    const float* W_e2t = (const float*)d_in[8];
    const float* W_t2t = (const float*)d_in[9];
    const float* g1    = (const float*)d_in[10];
    const float* b1    = (const float*)d_in[11];
    const float* g2    = (const float*)d_in[12];
    const float* b2    = (const float*)d_in[13];

    const int N = in_sizes[0] / D;   // 50000
    const int E = in_sizes[3];       // 500000

    float* eout = (float*)d_out;                    // [E,128]
    float* nout = eout + (size_t)E * D;             // [N,128]: agg, then tgt_out in place

    // workspace layout (Wbf first => 16B alignment for int4 loads)
    short* Wbf = (short*)d_ws;                      // 5 x [128][128] bf16
    float* Ps  = (float*)(Wbf + 5 * 16384);         // [N,128] f32
    float* Pt  = Ps + (size_t)N * D;
    float* Ptt = Pt + (size_t)N * D;
    int*   cnt    = (int*)(Ptt + (size_t)N * D);    // [N]
    int*   off    = cnt + N;                        // [N+1]
    int*   cursor = off + N + 1;                    // [N]
    int*   elist  = cursor + N;                     // [E]

    const short* Wb_s2e = Wbf;
    const short* Wb_t2e = Wbf + 1 * 16384;
    const short* Wb_e2t = Wbf + 3 * 16384;
    const short* Wb_t2t = Wbf + 4 * 16384;

    // ---- prep: weight conversion + hist zeroing ----
    const int zeroBlocks = (N + 255) / 256;
    k_prep<<<80 + zeroBlocks, 256, 0, stream>>>(W_s2e, W_t2e, W_e2e, W_e2t, W_t2t,
                                                Wbf, cnt, N);

    // ---- CSR build (int atomics only) ----
    k_hist<<<(E + 255) / 256, 256, 0, stream>>>(tidx, cnt, E);
    k_scan<<<1, 1024, 0, stream>>>(cnt, off, cursor, N);
    k_scatter<<<(E + 255) / 256, 256, 0, stream>>>(tidx, cursor, elist, E);

    // ---- node-side transforms: one fused launch ----
    const int ntilesN = N >> 4;                     // 3125
    const int nb = (ntilesN + 3) / 4;               // 782
    k_gemms<<<2 * nb, 256, 0, stream>>>(src, tgt, Wb_s2e, Wb_t2e, Wb_t2t,
                                        Ps, Pt, Ptt, ntilesN, nb);

    // ---- edge update (round-0 config), split for profiler visibility ----
    const int ntilesE = E >> 4;
    const int halfE = ntilesE >> 1;
    k_edge<<<1024, 256, 0, stream>>>(edge, sidx, tidx, W_e2e, Ps, Pt, g1, b1,
                                     eout, 0, halfE);
    k_edge<<<1024, 256, 0, stream>>>(edge, sidx, tidx, W_e2e, Ps, Pt, g1, b1,
                                     eout, halfE, ntilesE);

    // ---- deterministic aggregation + node update ----
    k_agg<<<(N + 3) / 4, 256, 0, stream>>>(eout, off, elist, nout, N);
    k_node_update<<<(ntilesN + 3) / 4, 256, 0, stream>>>(nout, Wb_e2t, Ptt, tgt,
                                                         g2, b2, nout, ntilesN);
}